// Round 6
// baseline (463.930 us; speedup 1.0000x reference)
//
#include <hip/hip_runtime.h>
#include <hip/hip_bf16.h>

typedef __bf16 bf16x8 __attribute__((ext_vector_type(8)));
typedef float  f32x4  __attribute__((ext_vector_type(4)));
typedef float  f32x16 __attribute__((ext_vector_type(16)));
typedef unsigned u32x2 __attribute__((ext_vector_type(2)));
typedef unsigned u32x4 __attribute__((ext_vector_type(4)));
typedef unsigned short u16;
typedef unsigned u32;
typedef unsigned long long u64;

#define L2E 1.44269504089f

__device__ __forceinline__ u16 f2b(float f) {
    __bf16 h = (__bf16)f;
    return __builtin_bit_cast(u16, h);
}

typedef const __attribute__((address_space(1))) void* gas1_t;
typedef __attribute__((address_space(3))) void* las3_t;

__device__ __forceinline__ void gl_lds16(const void* g, void* l) {
    __builtin_amdgcn_global_load_lds((gas1_t)g, (las3_t)l, 16, 0, 0);
}

// ---------------- prep kernels ----------------

__global__ void cvt_bf16(const float* __restrict__ in, u16* __restrict__ out, int n4) {
    int i = blockIdx.x * 256 + threadIdx.x;
    if (i < n4) {
        float4 v = ((const float4*)in)[i];
        u64 pk = (u64)f2b(v.x) | ((u64)f2b(v.y) << 16) | ((u64)f2b(v.z) << 32) | ((u64)f2b(v.w) << 48);
        ((u64*)out)[i] = pk;
    }
}

// Build Wqkv [3072,1024] bf16: rows 0-1023 Wq+2*Bq@Aq, 1024-2047 Wk, 2048-3071 Wv+2*Bv@Av
__global__ void prep_wqkv(const float* __restrict__ Wq, const float* __restrict__ Wk,
                          const float* __restrict__ Wv, const float* __restrict__ Aq,
                          const float* __restrict__ Bq, const float* __restrict__ Av,
                          const float* __restrict__ Bv, u16* __restrict__ out) {
    int idx = blockIdx.x * 256 + threadIdx.x;   // 0 .. 3072*1024
    int n = idx >> 10, j = idx & 1023;
    float v;
    if (n < 1024) {
        v = Wq[n * 1024 + j];
        const float* Br = Bq + n * 16;
        float s = 0.f;
#pragma unroll
        for (int r = 0; r < 16; ++r) s += Br[r] * Aq[r * 1024 + j];
        v += 2.0f * s;
    } else if (n < 2048) {
        v = Wk[(n - 1024) * 1024 + j];
    } else {
        int nn = n - 2048;
        v = Wv[nn * 1024 + j];
        const float* Br = Bv + nn * 16;
        float s = 0.f;
#pragma unroll
        for (int r = 0; r < 16; ++r) s += Br[r] * Av[r * 1024 + j];
        v += 2.0f * s;
    }
    out[idx] = f2b(v);
}

// ---------------- GEMM: C[M,N] = A[M,K] * W[N,K]^T (bf16 in, m97-style) ----------------

template <int EPI>
__global__ __launch_bounds__(256, 2)
void gemm_bt(const u16* __restrict__ A, const u16* __restrict__ W,
             float* __restrict__ Cout,
             u16* __restrict__ qo, u16* __restrict__ ko, u16* __restrict__ vo,
             int M, int N, int K) {
    __shared__ u16 ldsA[128 * 32];
    __shared__ u16 ldsW[128 * 32];
    const int t = threadIdx.x;
    const int l = t & 63;
    const int m0 = blockIdx.y * 128;
    const int n0 = blockIdx.x * 128;
    const int wm = (t >> 6) >> 1, wn = (t >> 6) & 1;
    const int lc = l & 15, lg = l >> 4;

    const int srow = t >> 2;
    const int sby = ((t & 3) * 16) ^ ((srow & 3) << 4);
    const size_t Ar0 = (size_t)(m0 + srow) * K, Ar1 = (size_t)(m0 + srow + 64) * K;
    const size_t Wr0 = (size_t)(n0 + srow) * K, Wr1 = (size_t)(n0 + srow + 64) * K;
    char* dA = (char*)ldsA;
    char* dW = (char*)ldsW;
    const int d0 = srow * 64 + (t & 3) * 16;
    const int d1 = d0 + 4096;

    f32x4 acc[4][4];
#pragma unroll
    for (int i = 0; i < 4; ++i)
#pragma unroll
        for (int j = 0; j < 4; ++j) acc[i][j] = (f32x4)0.f;

    for (int kt = 0; kt < K; kt += 32) {
        const size_t kb = (size_t)kt * 2;
        gl_lds16((const char*)A + Ar0 * 2 + kb + sby, dA + d0);
        gl_lds16((const char*)A + Ar1 * 2 + kb + sby, dA + d1);
        gl_lds16((const char*)W + Wr0 * 2 + kb + sby, dW + d0);
        gl_lds16((const char*)W + Wr1 * 2 + kb + sby, dW + d1);
        __syncthreads();
        bf16x8 af[4], wf[4];
#pragma unroll
        for (int mi = 0; mi < 4; ++mi) {
            int row = wm * 64 + mi * 16 + lc;
            af[mi] = *(const bf16x8*)(dA + row * 64 + ((lg * 16) ^ ((row & 3) << 4)));
        }
#pragma unroll
        for (int ni = 0; ni < 4; ++ni) {
            int row = wn * 64 + ni * 16 + lc;
            wf[ni] = *(const bf16x8*)(dW + row * 64 + ((lg * 16) ^ ((row & 3) << 4)));
        }
#pragma unroll
        for (int mi = 0; mi < 4; ++mi)
#pragma unroll
            for (int ni = 0; ni < 4; ++ni)
                acc[mi][ni] = __builtin_amdgcn_mfma_f32_16x16x32_bf16(af[mi], wf[ni], acc[mi][ni], 0, 0, 0);
        __syncthreads();
    }

    if (EPI == 0) {
#pragma unroll
        for (int mi = 0; mi < 4; ++mi) {
            int row = m0 + wm * 64 + mi * 16 + lg * 4;
#pragma unroll
            for (int ni = 0; ni < 4; ++ni) {
                int col = n0 + wn * 64 + ni * 16 + lc;
#pragma unroll
                for (int r = 0; r < 4; ++r)
                    Cout[(size_t)(row + r) * N + col] = acc[mi][ni][r];
            }
        }
    } else {
#pragma unroll
        for (int mi = 0; mi < 4; ++mi) {
#pragma unroll
            for (int ni = 0; ni < 4; ++ni) {
                int n = n0 + wn * 64 + ni * 16 + lc;
                int which = n >> 10, inner = n & 1023;
                int h = inner >> 6, dk = inner & 63;
#pragma unroll
                for (int r = 0; r < 4; ++r) {
                    int mrow = m0 + wm * 64 + mi * 16 + lg * 4 + r;
                    int b = mrow >> 11, s = mrow & 2047;
                    size_t bh = (size_t)(b * 16 + h);
                    u16 v = f2b(acc[mi][ni][r]);
                    if (which == 0)      qo[(bh * 2048 + s) * 64 + dk] = v;
                    else if (which == 1) ko[(bh * 2048 + s) * 64 + dk] = v;
                    else                 vo[(bh * 64 + dk) * 2048 + s] = v;
                }
            }
        }
    }
}

// ---------------- flash attention with additive bias ----------------
// block = (b, h, 128 q); 4 waves x 32 q. 32x32x16 MFMA, swapped QK^T
// (mfma(K,Q)): each lane holds a 64-wide P-row slice in 32 f32 regs ->
// softmax fully in-register (no-max: scores bounded), P->PV A-frags via
// 16 cvt_pk_bf16 + 8 permlane32_swap (T12), no P LDS round-trip.
// K/V double-buffered LDS via global_load_lds (source-pre-swizzled).
// Counted-vmcnt barrier keeps 8 bias loads in flight across it.

__global__ __launch_bounds__(256, 4)
void attn(const u16* __restrict__ Qg, const u16* __restrict__ Kg,
          const u16* __restrict__ Vg, const float* __restrict__ bias,
          u16* __restrict__ Og) {
    __shared__ u16 Kb[2][4096];    // [64 kv][64 dk], 8KB each
    __shared__ u16 Vb[2][4096];    // [64 dk][64 kv], 8KB each
    const int t = threadIdx.x;
    const int l = t & 63;
    const int w = t >> 6;                 // wave = q-subtile
    const int bid = blockIdx.x;
    const int h = bid & 15, b = (bid >> 4) & 3, qt = bid >> 6;
    const int q0 = qt * 128 + w * 32;
    const int l31 = l & 31, L5 = l >> 5;
    const int rkey = (l & 7) << 4;        // read swizzle: rows have row&7 == l&7
    const size_t bh = (size_t)b * 16 + h;
    const u16* Qp = Qg + bh * 2048 * 64;
    const char* Kpb = (const char*)(Kg + bh * 2048 * 64);  // [kv][dk] rows 128B
    const char* Vpb = (const char*)(Vg + bh * 64 * 2048);  // [dk][kv] rows 4096B

    // staging geometry (pre-swizzled source, linear LDS dest)
    const int row0 = w * 8 + (l >> 3);
    const int row1 = row0 + 32;
    const int scol2 = ((l & 7) * 16) ^ (((l >> 3) & 7) << 4);
    const int ldst = w * 1024 + l * 16;

    // stage kt=0 FIRST (oldest in vmem queue)
    gl_lds16(Kpb + (size_t)row0 * 128 + scol2, (char*)Kb[0] + ldst);
    gl_lds16(Kpb + (size_t)row1 * 128 + scol2, (char*)Kb[0] + 4096 + ldst);
    gl_lds16(Vpb + (size_t)row0 * 4096 + scol2, (char*)Vb[0] + ldst);
    gl_lds16(Vpb + (size_t)row1 * 4096 + scol2, (char*)Vb[0] + 4096 + ldst);
    asm volatile("" ::: "memory");

    // Q fragments: B-frag [col=q=l31][k = dstep*16 + L5*8 + j], live whole kernel
    bf16x8 qf[4];
#pragma unroll
    for (int d = 0; d < 4; ++d)
        qf[d] = *(const bf16x8*)&Qp[(size_t)(q0 + l31) * 64 + d * 16 + L5 * 8];

    f32x16 acc[2];
#pragma unroll
    for (int o = 0; o < 2; ++o) acc[o] = (f32x16)0.f;
    f32x4 lsum4 = (f32x4)0.f;

    // bias: br[ni][blk] = float4 at k = kt*64 + ni*32 + blk*8 + 4*L5, q row = q0+l31
    const float* bp0 = bias + ((size_t)h * 2048 + q0 + l31) * 2048 + 4 * L5;
    float4 br[2][4];
#pragma unroll
    for (int ni = 0; ni < 2; ++ni)
#pragma unroll
        for (int blk = 0; blk < 4; ++blk)
            br[ni][blk] = *(const float4*)(bp0 + ni * 32 + blk * 8);

    // drain staging+qf; bias may stay in flight
    asm volatile("s_waitcnt vmcnt(8)\n\ts_barrier" ::: "memory");

    for (int kt = 0; kt < 32; ++kt) {
        const int cur = kt & 1;
        const int k0 = kt * 64;

        // TOP: stage K/V for kt+1 (oldest vmem ops this iter)
        if (kt < 31) {
            const size_t kb = (size_t)(k0 + 64);
            gl_lds16(Kpb + (kb + row0) * 128 + scol2, (char*)Kb[cur ^ 1] + ldst);
            gl_lds16(Kpb + (kb + row1) * 128 + scol2, (char*)Kb[cur ^ 1] + 4096 + ldst);
            gl_lds16(Vpb + (size_t)row0 * 4096 + kb * 2 + scol2, (char*)Vb[cur ^ 1] + ldst);
            gl_lds16(Vpb + (size_t)row1 * 4096 + kb * 2 + scol2, (char*)Vb[cur ^ 1] + 4096 + ldst);
        }
        asm volatile("" ::: "memory");

        // QK^T swapped (A=K, B=Q), 32x32x16: sfr[ni] reg r -> S^T at
        // k = ni*32 + (r&3)+8*(r>>2)+4*L5, q = q0 + l31
        f32x16 sfr[2];
#pragma unroll
        for (int ni = 0; ni < 2; ++ni) {
            bf16x8 kf[4];
#pragma unroll
            for (int d = 0; d < 4; ++d)
                kf[d] = *(const bf16x8*)((const char*)Kb[cur] + (ni * 32 + l31) * 128 + ((d * 32 + L5 * 16) ^ rkey));
            __builtin_amdgcn_s_setprio(1);
            sfr[ni] = __builtin_amdgcn_mfma_f32_32x32x16_bf16(kf[0], qf[0], (f32x16)0.f, 0, 0, 0);
#pragma unroll
            for (int d = 1; d < 4; ++d)
                sfr[ni] = __builtin_amdgcn_mfma_f32_32x32x16_bf16(kf[d], qf[d], sfr[ni], 0, 0, 0);
            __builtin_amdgcn_s_setprio(0);
        }

        // softmax (no max): P = exp2((S+bias)*log2e); pack to bf16 dwords
        u32 Dv[2][4][2];
#pragma unroll
        for (int ni = 0; ni < 2; ++ni)
#pragma unroll
            for (int blk = 0; blk < 4; ++blk) {
                f32x4 pv;
#pragma unroll
                for (int off = 0; off < 4; ++off)
                    pv[off] = __builtin_amdgcn_exp2f((sfr[ni][blk * 4 + off] + (&br[ni][blk].x)[off]) * L2E);
                lsum4 += pv;
                asm("v_cvt_pk_bf16_f32 %0, %1, %2" : "=v"(Dv[ni][blk][0]) : "v"(pv[0]), "v"(pv[1]));
                asm("v_cvt_pk_bf16_f32 %0, %1, %2" : "=v"(Dv[ni][blk][1]) : "v"(pv[2]), "v"(pv[3]));
            }

        // in-register P relayout -> PV A-frags (8 permlane32_swap)
        u32x4 pw[4];
#pragma unroll
        for (int ni = 0; ni < 2; ++ni)
#pragma unroll
            for (int ke = 0; ke < 2; ++ke)
#pragma unroll
                for (int c = 0; c < 2; ++c) {
                    u32x2 r = __builtin_amdgcn_permlane32_swap(Dv[ni][2 * ke][c], Dv[ni][2 * ke + 1][c], false, false);
                    pw[ni * 2 + ke][c] = r[0];
                    pw[ni * 2 + ke][2 + c] = r[1];
                }
        bf16x8 pf[4];
#pragma unroll
        for (int ks = 0; ks < 4; ++ks) pf[ks] = __builtin_bit_cast(bf16x8, pw[ks]);

        // prefetch bias for kt+1 (stays in flight across the barrier)
        if (kt < 31) {
#pragma unroll
            for (int ni = 0; ni < 2; ++ni)
#pragma unroll
                for (int blk = 0; blk < 4; ++blk)
                    br[ni][blk] = *(const float4*)(bp0 + k0 + 64 + ni * 32 + blk * 8);
        }

        // PV: A = P (regs), B = V (LDS): O[q][dk], acc[o] 32x32
#pragma unroll
        for (int o = 0; o < 2; ++o) {
            bf16x8 vf[4];
#pragma unroll
            for (int ks = 0; ks < 4; ++ks)
                vf[ks] = *(const bf16x8*)((const char*)Vb[cur] + (o * 32 + l31) * 128 + ((ks * 32 + L5 * 16) ^ rkey));
            __builtin_amdgcn_s_setprio(1);
#pragma unroll
            for (int ks = 0; ks < 4; ++ks)
                acc[o] = __builtin_amdgcn_mfma_f32_32x32x16_bf16(pf[ks], vf[ks], acc[o], 0, 0, 0);
            __builtin_amdgcn_s_setprio(0);
        }

        // counted barrier: drain only the 4 staging DMAs; bias8 stays in flight
        asm volatile("s_waitcnt vmcnt(8)\n\ts_barrier" ::: "memory");
    }

    // row-sum: lane-local horizontal + xor32 (lane l and l+32 share q-row)
    float ls = (lsum4[0] + lsum4[1]) + (lsum4[2] + lsum4[3]);
    ls += __shfl_xor(ls, 32);
    float inv = 1.0f / ls;                 // inv for q-row = l31 (lanes 0..31 hold rows 0..31)
    float invr[16];
#pragma unroll
    for (int r = 0; r < 16; ++r)
        invr[r] = __shfl(inv, (r & 3) + 8 * (r >> 2) + 4 * L5);

    // epilogue: C layout row = (r&3)+8*(r>>2)+4*L5 (q), col = l31 (dk)
#pragma unroll
    for (int o = 0; o < 2; ++o)
#pragma unroll
        for (int r = 0; r < 16; ++r) {
            int rowr = (r & 3) + 8 * (r >> 2) + 4 * L5;
            Og[((size_t)b * 2048 + q0 + rowr) * 1024 + h * 64 + o * 32 + l31] = f2b(acc[o][r] * invr[r]);
        }
}

// ---------------- launch ----------------

extern "C" void kernel_launch(void* const* d_in, const int* in_sizes, int n_in,
                              void* d_out, int out_size, void* d_ws, size_t ws_size,
                              hipStream_t stream) {
    const float* x    = (const float*)d_in[0];
    const float* bias = (const float*)d_in[1];
    const float* Wq   = (const float*)d_in[2];
    const float* Wk   = (const float*)d_in[3];
    const float* Wv   = (const float*)d_in[4];
    const float* Wo   = (const float*)d_in[5];
    const float* Aq   = (const float*)d_in[6];
    const float* Bq   = (const float*)d_in[7];
    const float* Av   = (const float*)d_in[8];
    const float* Bv   = (const float*)d_in[9];
    float* out = (float*)d_out;

    char* ws = (char*)d_ws;
    u16* xb   = (u16*)(ws);                       // 16MB [8192,1024]; reused as attn output
    u16* wqkv = (u16*)(ws + (16ull << 20));       // 6MB  [3072,1024]
    u16* wob  = (u16*)(ws + (22ull << 20));       // 2MB  [1024,1024]
    u16* qw   = (u16*)(ws + (24ull << 20));       // 16MB [B,H,S,DK]
    u16* kw   = (u16*)(ws + (40ull << 20));       // 16MB [B,H,S,DK]
    u16* vw   = (u16*)(ws + (56ull << 20));       // 16MB [B,H,DK,S]

    cvt_bf16<<<8192, 256, 0, stream>>>(x, xb, 2097152);
    cvt_bf16<<<1024, 256, 0, stream>>>(Wo, wob, 262144);
    prep_wqkv<<<12288, 256, 0, stream>>>(Wq, Wk, Wv, Aq, Bq, Av, Bv, wqkv);
    gemm_bt<1><<<dim3(24, 64), 256, 0, stream>>>(xb, wqkv, nullptr, qw, kw, vw, 8192, 3072, 1024);
    attn<<<1024, 256, 0, stream>>>(qw, kw, vw, bias, xb);
    gemm_bt<0><<<dim3(8, 64), 256, 0, stream>>>(xb, wob, out, nullptr, nullptr, nullptr, 8192, 1024, 1024);
}

// Round 7
// 324.903 us; speedup vs baseline: 1.4279x; 1.4279x over previous
//
#include <hip/hip_runtime.h>
#include <hip/hip_bf16.h>

typedef __bf16 bf16x8 __attribute__((ext_vector_type(8)));
typedef float  f32x4  __attribute__((ext_vector_type(4)));
typedef float  f32x16 __attribute__((ext_vector_type(16)));
typedef unsigned u32x2 __attribute__((ext_vector_type(2)));
typedef unsigned u32x4 __attribute__((ext_vector_type(4)));
typedef unsigned short u16;
typedef unsigned u32;
typedef unsigned long long u64;

#define L2E 1.44269504089f

__device__ __forceinline__ u16 f2b(float f) {
    __bf16 h = (__bf16)f;
    return __builtin_bit_cast(u16, h);
}

typedef const __attribute__((address_space(1))) void* gas1_t;
typedef __attribute__((address_space(3))) void* las3_t;

__device__ __forceinline__ void gl_lds16(const void* g, void* l) {
    __builtin_amdgcn_global_load_lds((gas1_t)g, (las3_t)l, 16, 0, 0);
}

// ---------------- prep kernels ----------------

__global__ void cvt_bf16(const float* __restrict__ in, u16* __restrict__ out, int n4) {
    int i = blockIdx.x * 256 + threadIdx.x;
    if (i < n4) {
        float4 v = ((const float4*)in)[i];
        u64 pk = (u64)f2b(v.x) | ((u64)f2b(v.y) << 16) | ((u64)f2b(v.z) << 32) | ((u64)f2b(v.w) << 48);
        ((u64*)out)[i] = pk;
    }
}

// Build Wqkv [3072,1024] bf16: rows 0-1023 Wq+2*Bq@Aq, 1024-2047 Wk, 2048-3071 Wv+2*Bv@Av
__global__ void prep_wqkv(const float* __restrict__ Wq, const float* __restrict__ Wk,
                          const float* __restrict__ Wv, const float* __restrict__ Aq,
                          const float* __restrict__ Bq, const float* __restrict__ Av,
                          const float* __restrict__ Bv, u16* __restrict__ out) {
    int idx = blockIdx.x * 256 + threadIdx.x;   // 0 .. 3072*1024
    int n = idx >> 10, j = idx & 1023;
    float v;
    if (n < 1024) {
        v = Wq[n * 1024 + j];
        const float* Br = Bq + n * 16;
        float s = 0.f;
#pragma unroll
        for (int r = 0; r < 16; ++r) s += Br[r] * Aq[r * 1024 + j];
        v += 2.0f * s;
    } else if (n < 2048) {
        v = Wk[(n - 1024) * 1024 + j];
    } else {
        int nn = n - 2048;
        v = Wv[nn * 1024 + j];
        const float* Br = Bv + nn * 16;
        float s = 0.f;
#pragma unroll
        for (int r = 0; r < 16; ++r) s += Br[r] * Av[r * 1024 + j];
        v += 2.0f * s;
    }
    out[idx] = f2b(v);
}

// ---------------- GEMM: C[M,N] = A[M,K] * W[N,K]^T (bf16 in, m97-style) ----------------

template <int EPI>
__global__ __launch_bounds__(256, 2)
void gemm_bt(const u16* __restrict__ A, const u16* __restrict__ W,
             float* __restrict__ Cout,
             u16* __restrict__ qo, u16* __restrict__ ko, u16* __restrict__ vo,
             int M, int N, int K) {
    __shared__ u16 ldsA[128 * 32];
    __shared__ u16 ldsW[128 * 32];
    const int t = threadIdx.x;
    const int l = t & 63;
    const int m0 = blockIdx.y * 128;
    const int n0 = blockIdx.x * 128;
    const int wm = (t >> 6) >> 1, wn = (t >> 6) & 1;
    const int lc = l & 15, lg = l >> 4;

    const int srow = t >> 2;
    const int sby = ((t & 3) * 16) ^ ((srow & 3) << 4);
    const size_t Ar0 = (size_t)(m0 + srow) * K, Ar1 = (size_t)(m0 + srow + 64) * K;
    const size_t Wr0 = (size_t)(n0 + srow) * K, Wr1 = (size_t)(n0 + srow + 64) * K;
    char* dA = (char*)ldsA;
    char* dW = (char*)ldsW;
    const int d0 = srow * 64 + (t & 3) * 16;
    const int d1 = d0 + 4096;

    f32x4 acc[4][4];
#pragma unroll
    for (int i = 0; i < 4; ++i)
#pragma unroll
        for (int j = 0; j < 4; ++j) acc[i][j] = (f32x4)0.f;

    for (int kt = 0; kt < K; kt += 32) {
        const size_t kb = (size_t)kt * 2;
        gl_lds16((const char*)A + Ar0 * 2 + kb + sby, dA + d0);
        gl_lds16((const char*)A + Ar1 * 2 + kb + sby, dA + d1);
        gl_lds16((const char*)W + Wr0 * 2 + kb + sby, dW + d0);
        gl_lds16((const char*)W + Wr1 * 2 + kb + sby, dW + d1);
        __syncthreads();
        bf16x8 af[4], wf[4];
#pragma unroll
        for (int mi = 0; mi < 4; ++mi) {
            int row = wm * 64 + mi * 16 + lc;
            af[mi] = *(const bf16x8*)(dA + row * 64 + ((lg * 16) ^ ((row & 3) << 4)));
        }
#pragma unroll
        for (int ni = 0; ni < 4; ++ni) {
            int row = wn * 64 + ni * 16 + lc;
            wf[ni] = *(const bf16x8*)(dW + row * 64 + ((lg * 16) ^ ((row & 3) << 4)));
        }
#pragma unroll
        for (int mi = 0; mi < 4; ++mi)
#pragma unroll
            for (int ni = 0; ni < 4; ++ni)
                acc[mi][ni] = __builtin_amdgcn_mfma_f32_16x16x32_bf16(af[mi], wf[ni], acc[mi][ni], 0, 0, 0);
        __syncthreads();
    }

    if (EPI == 0) {
#pragma unroll
        for (int mi = 0; mi < 4; ++mi) {
            int row = m0 + wm * 64 + mi * 16 + lg * 4;
#pragma unroll
            for (int ni = 0; ni < 4; ++ni) {
                int col = n0 + wn * 64 + ni * 16 + lc;
#pragma unroll
                for (int r = 0; r < 4; ++r)
                    Cout[(size_t)(row + r) * N + col] = acc[mi][ni][r];
            }
        }
    } else {
#pragma unroll
        for (int mi = 0; mi < 4; ++mi) {
#pragma unroll
            for (int ni = 0; ni < 4; ++ni) {
                int n = n0 + wn * 64 + ni * 16 + lc;
                int which = n >> 10, inner = n & 1023;
                int h = inner >> 6, dk = inner & 63;
#pragma unroll
                for (int r = 0; r < 4; ++r) {
                    int mrow = m0 + wm * 64 + mi * 16 + lg * 4 + r;
                    int b = mrow >> 11, s = mrow & 2047;
                    size_t bh = (size_t)(b * 16 + h);
                    u16 v = f2b(acc[mi][ni][r]);
                    if (which == 0)      qo[(bh * 2048 + s) * 64 + dk] = v;
                    else if (which == 1) ko[(bh * 2048 + s) * 64 + dk] = v;
                    else                 vo[(bh * 64 + dk) * 2048 + s] = v;
                }
            }
        }
    }
}

// ---------------- flash attention with additive bias ----------------
// block = (b, h, 128 q); 4 waves x 32 q. 32x32x16 MFMA, swapped QK^T
// (mfma(K,Q)): each lane holds a 64-wide P-row slice in 32 f32 regs ->
// softmax fully in-register (no-max: scores bounded), P->PV A-frags via
// 16 cvt_pk_bf16 + 8 permlane32_swap (T12), no P LDS round-trip.
// K/V double-buffered LDS via global_load_lds (source-pre-swizzled).
// Counted-vmcnt barrier keeps 8 bias loads in flight across it.
// launch_bounds(256,3): VGPR cap ~170 fits peak live set (~160) with NO
// scratch spill -- (256,4) capped at 128 and spilled 290MB/dispatch (R6).

__global__ __launch_bounds__(256, 3)
void attn(const u16* __restrict__ Qg, const u16* __restrict__ Kg,
          const u16* __restrict__ Vg, const float* __restrict__ bias,
          u16* __restrict__ Og) {
    __shared__ u16 Kb[2][4096];    // [64 kv][64 dk], 8KB each
    __shared__ u16 Vb[2][4096];    // [64 dk][64 kv], 8KB each
    const int t = threadIdx.x;
    const int l = t & 63;
    const int w = t >> 6;                 // wave = q-subtile
    const int bid = blockIdx.x;
    const int h = bid & 15, b = (bid >> 4) & 3, qt = bid >> 6;
    const int q0 = qt * 128 + w * 32;
    const int l31 = l & 31, L5 = l >> 5;
    const int rkey = (l & 7) << 4;        // read swizzle: rows have row&7 == l&7
    const size_t bh = (size_t)b * 16 + h;
    const u16* Qp = Qg + bh * 2048 * 64;
    const char* Kpb = (const char*)(Kg + bh * 2048 * 64);  // [kv][dk] rows 128B
    const char* Vpb = (const char*)(Vg + bh * 64 * 2048);  // [dk][kv] rows 4096B

    // staging geometry (pre-swizzled source, linear LDS dest)
    const int row0 = w * 8 + (l >> 3);
    const int row1 = row0 + 32;
    const int scol2 = ((l & 7) * 16) ^ (((l >> 3) & 7) << 4);
    const int ldst = w * 1024 + l * 16;

    // stage kt=0 FIRST (oldest in vmem queue)
    gl_lds16(Kpb + (size_t)row0 * 128 + scol2, (char*)Kb[0] + ldst);
    gl_lds16(Kpb + (size_t)row1 * 128 + scol2, (char*)Kb[0] + 4096 + ldst);
    gl_lds16(Vpb + (size_t)row0 * 4096 + scol2, (char*)Vb[0] + ldst);
    gl_lds16(Vpb + (size_t)row1 * 4096 + scol2, (char*)Vb[0] + 4096 + ldst);
    asm volatile("" ::: "memory");

    // Q fragments: B-frag [col=q=l31][k = dstep*16 + L5*8 + j], live whole kernel
    bf16x8 qf[4];
#pragma unroll
    for (int d = 0; d < 4; ++d)
        qf[d] = *(const bf16x8*)&Qp[(size_t)(q0 + l31) * 64 + d * 16 + L5 * 8];

    f32x16 acc[2];
#pragma unroll
    for (int o = 0; o < 2; ++o) acc[o] = (f32x16)0.f;
    f32x4 lsum4 = (f32x4)0.f;

    // bias: br[ni][blk] = float4 at k = kt*64 + ni*32 + blk*8 + 4*L5, q row = q0+l31
    const float* bp0 = bias + ((size_t)h * 2048 + q0 + l31) * 2048 + 4 * L5;
    float4 br[2][4];
#pragma unroll
    for (int ni = 0; ni < 2; ++ni)
#pragma unroll
        for (int blk = 0; blk < 4; ++blk)
            br[ni][blk] = *(const float4*)(bp0 + ni * 32 + blk * 8);

    // drain staging+qf; bias may stay in flight
    asm volatile("s_waitcnt vmcnt(8)\n\ts_barrier" ::: "memory");

    for (int kt = 0; kt < 32; ++kt) {
        const int cur = kt & 1;
        const int k0 = kt * 64;

        // TOP: stage K/V for kt+1 (oldest vmem ops this iter)
        if (kt < 31) {
            const size_t kb = (size_t)(k0 + 64);
            gl_lds16(Kpb + (kb + row0) * 128 + scol2, (char*)Kb[cur ^ 1] + ldst);
            gl_lds16(Kpb + (kb + row1) * 128 + scol2, (char*)Kb[cur ^ 1] + 4096 + ldst);
            gl_lds16(Vpb + (size_t)row0 * 4096 + kb * 2 + scol2, (char*)Vb[cur ^ 1] + ldst);
            gl_lds16(Vpb + (size_t)row1 * 4096 + kb * 2 + scol2, (char*)Vb[cur ^ 1] + 4096 + ldst);
        }
        asm volatile("" ::: "memory");

        // QK^T swapped (A=K, B=Q), 32x32x16: sfr[ni] reg r -> S^T at
        // k = ni*32 + (r&3)+8*(r>>2)+4*L5, q = q0 + l31
        f32x16 sfr[2];
#pragma unroll
        for (int ni = 0; ni < 2; ++ni) {
            bf16x8 kf[4];
#pragma unroll
            for (int d = 0; d < 4; ++d)
                kf[d] = *(const bf16x8*)((const char*)Kb[cur] + (ni * 32 + l31) * 128 + ((d * 32 + L5 * 16) ^ rkey));
            __builtin_amdgcn_s_setprio(1);
            sfr[ni] = __builtin_amdgcn_mfma_f32_32x32x16_bf16(kf[0], qf[0], (f32x16)0.f, 0, 0, 0);
#pragma unroll
            for (int d = 1; d < 4; ++d)
                sfr[ni] = __builtin_amdgcn_mfma_f32_32x32x16_bf16(kf[d], qf[d], sfr[ni], 0, 0, 0);
            __builtin_amdgcn_s_setprio(0);
        }

        // softmax (no max): P = exp2((S+bias)*log2e); pack to bf16 dwords
        u32 Dv[2][4][2];
#pragma unroll
        for (int ni = 0; ni < 2; ++ni)
#pragma unroll
            for (int blk = 0; blk < 4; ++blk) {
                f32x4 pv;
#pragma unroll
                for (int off = 0; off < 4; ++off)
                    pv[off] = __builtin_amdgcn_exp2f((sfr[ni][blk * 4 + off] + (&br[ni][blk].x)[off]) * L2E);
                lsum4 += pv;
                asm("v_cvt_pk_bf16_f32 %0, %1, %2" : "=v"(Dv[ni][blk][0]) : "v"(pv[0]), "v"(pv[1]));
                asm("v_cvt_pk_bf16_f32 %0, %1, %2" : "=v"(Dv[ni][blk][1]) : "v"(pv[2]), "v"(pv[3]));
            }

        // in-register P relayout -> PV A-frags (8 permlane32_swap)
        u32x4 pw[4];
#pragma unroll
        for (int ni = 0; ni < 2; ++ni)
#pragma unroll
            for (int ke = 0; ke < 2; ++ke)
#pragma unroll
                for (int c = 0; c < 2; ++c) {
                    u32x2 r = __builtin_amdgcn_permlane32_swap(Dv[ni][2 * ke][c], Dv[ni][2 * ke + 1][c], false, false);
                    pw[ni * 2 + ke][c] = r[0];
                    pw[ni * 2 + ke][2 + c] = r[1];
                }
        bf16x8 pf[4];
#pragma unroll
        for (int ks = 0; ks < 4; ++ks) pf[ks] = __builtin_bit_cast(bf16x8, pw[ks]);

        // prefetch bias for kt+1 (stays in flight across the barrier)
        if (kt < 31) {
#pragma unroll
            for (int ni = 0; ni < 2; ++ni)
#pragma unroll
                for (int blk = 0; blk < 4; ++blk)
                    br[ni][blk] = *(const float4*)(bp0 + k0 + 64 + ni * 32 + blk * 8);
        }

        // PV: A = P (regs), B = V (LDS): O[q][dk], acc[o] 32x32
#pragma unroll
        for (int o = 0; o < 2; ++o) {
            bf16x8 vf[4];
#pragma unroll
            for (int ks = 0; ks < 4; ++ks)
                vf[ks] = *(const bf16x8*)((const char*)Vb[cur] + (o * 32 + l31) * 128 + ((ks * 32 + L5 * 16) ^ rkey));
            __builtin_amdgcn_s_setprio(1);
#pragma unroll
            for (int ks = 0; ks < 4; ++ks)
                acc[o] = __builtin_amdgcn_mfma_f32_32x32x16_bf16(pf[ks], vf[ks], acc[o], 0, 0, 0);
            __builtin_amdgcn_s_setprio(0);
        }

        // counted barrier: drain only the 4 staging DMAs; bias8 stays in flight
        asm volatile("s_waitcnt vmcnt(8)\n\ts_barrier" ::: "memory");
    }

    // row-sum: lane-local horizontal + xor32 (lane l and l+32 share q-row)
    float ls = (lsum4[0] + lsum4[1]) + (lsum4[2] + lsum4[3]);
    ls += __shfl_xor(ls, 32);
    float inv = 1.0f / ls;                 // inv for q-row = l31 (lanes 0..31 hold rows 0..31)
    float invr[16];
#pragma unroll
    for (int r = 0; r < 16; ++r)
        invr[r] = __shfl(inv, (r & 3) + 8 * (r >> 2) + 4 * L5);

    // epilogue: C layout row = (r&3)+8*(r>>2)+4*L5 (q), col = l31 (dk)
#pragma unroll
    for (int o = 0; o < 2; ++o)
#pragma unroll
        for (int r = 0; r < 16; ++r) {
            int rowr = (r & 3) + 8 * (r >> 2) + 4 * L5;
            Og[((size_t)b * 2048 + q0 + rowr) * 1024 + h * 64 + o * 32 + l31] = f2b(acc[o][r] * invr[r]);
        }
}

// ---------------- launch ----------------

extern "C" void kernel_launch(void* const* d_in, const int* in_sizes, int n_in,
                              void* d_out, int out_size, void* d_ws, size_t ws_size,
                              hipStream_t stream) {
    const float* x    = (const float*)d_in[0];
    const float* bias = (const float*)d_in[1];
    const float* Wq   = (const float*)d_in[2];
    const float* Wk   = (const float*)d_in[3];
    const float* Wv   = (const float*)d_in[4];
    const float* Wo   = (const float*)d_in[5];
    const float* Aq   = (const float*)d_in[6];
    const float* Bq   = (const float*)d_in[7];
    const float* Av   = (const float*)d_in[8];
    const float* Bv   = (const float*)d_in[9];
    float* out = (float*)d_out;

    char* ws = (char*)d_ws;
    u16* xb   = (u16*)(ws);                       // 16MB [8192,1024]; reused as attn output
    u16* wqkv = (u16*)(ws + (16ull << 20));       // 6MB  [3072,1024]
    u16* wob  = (u16*)(ws + (22ull << 20));       // 2MB  [1024,1024]
    u16* qw   = (u16*)(ws + (24ull << 20));       // 16MB [B,H,S,DK]
    u16* kw   = (u16*)(ws + (40ull << 20));       // 16MB [B,H,S,DK]
    u16* vw   = (u16*)(ws + (56ull << 20));       // 16MB [B,H,DK,S]

    cvt_bf16<<<8192, 256, 0, stream>>>(x, xb, 2097152);
    cvt_bf16<<<1024, 256, 0, stream>>>(Wo, wob, 262144);
    prep_wqkv<<<12288, 256, 0, stream>>>(Wq, Wk, Wv, Aq, Bq, Av, Bv, wqkv);
    gemm_bt<1><<<dim3(24, 64), 256, 0, stream>>>(xb, wqkv, nullptr, qw, kw, vw, 8192, 3072, 1024);
    attn<<<1024, 256, 0, stream>>>(qw, kw, vw, bias, xb);
    gemm_bt<0><<<dim3(8, 64), 256, 0, stream>>>(xb, wob, out, nullptr, nullptr, nullptr, 8192, 1024, 1024);
}